// Round 1
// baseline (1498.597 us; speedup 1.0000x reference)
//
#include <hip/hip_runtime.h>
#include <hip/hip_bf16.h>

#define B_ 32
#define N_ 785
#define C_ 512
#define NH 8
#define CH 64
#define HW_ 784
#define M_ (B_ * N_)  // 25120

// ---------------------------------------------------------------------------
// QKV GEMM: Y[m][j] = sum_k X[m][k] * W[j][k];  M=25120, Ncols=1536, K=512
// Scatter into q/k/v laid out (B, NH, N, CH).
// ---------------------------------------------------------------------------
__global__ __launch_bounds__(256) void gemm_qkv(const float* __restrict__ X,
                                                const float* __restrict__ W,
                                                float* __restrict__ q,
                                                float* __restrict__ k,
                                                float* __restrict__ v) {
  __shared__ float As[16][68];
  __shared__ float Bs[16][68];
  const int t = threadIdx.x;
  const int row0 = blockIdx.y * 64, col0 = blockIdx.x * 64;
  const int lr = t >> 2, lk = (t & 3) << 2;
  const int tx = t & 15, ty = t >> 4;
  float acc[4][4] = {};
  for (int k0 = 0; k0 < 512; k0 += 16) {
    float4 a4 = make_float4(0.f, 0.f, 0.f, 0.f);
    const int gr = row0 + lr;
    if (gr < M_) a4 = *(const float4*)(X + (size_t)gr * 512 + k0 + lk);
    As[lk + 0][lr] = a4.x; As[lk + 1][lr] = a4.y;
    As[lk + 2][lr] = a4.z; As[lk + 3][lr] = a4.w;
    const float4 b4 = *(const float4*)(W + (size_t)(col0 + lr) * 512 + k0 + lk);
    Bs[lk + 0][lr] = b4.x; Bs[lk + 1][lr] = b4.y;
    Bs[lk + 2][lr] = b4.z; Bs[lk + 3][lr] = b4.w;
    __syncthreads();
#pragma unroll
    for (int kk = 0; kk < 16; ++kk) {
      const float4 a = *(const float4*)&As[kk][ty << 2];
      const float4 b = *(const float4*)&Bs[kk][tx << 2];
      const float av[4] = {a.x, a.y, a.z, a.w};
      const float bv[4] = {b.x, b.y, b.z, b.w};
#pragma unroll
      for (int i = 0; i < 4; ++i)
#pragma unroll
        for (int j = 0; j < 4; ++j) acc[i][j] = fmaf(av[i], bv[j], acc[i][j]);
    }
    __syncthreads();
  }
#pragma unroll
  for (int i = 0; i < 4; ++i) {
    const int m = row0 + (ty << 2) + i;
    if (m >= M_) break;
    const int b = m / N_, n = m % N_;
#pragma unroll
    for (int j = 0; j < 4; ++j) {
      const int col = col0 + (tx << 2) + j;
      const int ts = col >> 9, head = (col >> 6) & 7, c = col & 63;
      float* dst = (ts == 0) ? q : ((ts == 1) ? k : v);
      dst[(((size_t)b * NH + head) * N_ + n) * CH + c] = acc[i][j];
    }
  }
}

// ---------------------------------------------------------------------------
// Per (b,h): softmax over N per channel of k (online), then
// kv[c][d] = sum_n softmax(k)[n][c] * v[n][d]   (64x64, K=785)
// ---------------------------------------------------------------------------
__global__ __launch_bounds__(256) void kv_kernel(const float* __restrict__ k,
                                                 const float* __restrict__ v,
                                                 float* __restrict__ kvout) {
  const int bh = blockIdx.x;
  const float* kp = k + (size_t)bh * N_ * CH;
  const float* vp = v + (size_t)bh * N_ * CH;
  const int t = threadIdx.x;
  const int c = t & 63, g = t >> 6;
  __shared__ float smax[4][64], ssum[4][64];
  __shared__ float maxc[64], invc[64];
  // phase 1: per-channel online max/sum over n
  float m = -1e30f, s = 0.f;
  for (int n = g; n < N_; n += 4) {
    const float x = kp[(size_t)n * CH + c];
    const float mn = fmaxf(m, x);
    s = s * __expf(m - mn) + __expf(x - mn);
    m = mn;
  }
  smax[g][c] = m; ssum[g][c] = s;
  __syncthreads();
  if (t < 64) {
    float mm = smax[0][t];
#pragma unroll
    for (int i = 1; i < 4; ++i) mm = fmaxf(mm, smax[i][t]);
    float ss = 0.f;
#pragma unroll
    for (int i = 0; i < 4; ++i) ss += ssum[i][t] * __expf(smax[i][t] - mm);
    maxc[t] = mm; invc[t] = 1.f / ss;
  }
  __syncthreads();
  // phase 2: tiled GEMM over n
  __shared__ float Ks[32][68];
  __shared__ float Vs[32][68];
  const int tx = t & 15, ty = t >> 4;
  float acc[4][4] = {};
  for (int n0 = 0; n0 < N_; n0 += 32) {
#pragma unroll
    for (int half = 0; half < 2; ++half) {
      const int lin = half * 1024 + t * 4;
      const int nl = lin >> 6, c4 = lin & 63;
      const int n = n0 + nl;
      if (n < N_) {
        const float4 k4 = *(const float4*)(kp + (size_t)n * CH + c4);
        const float4 v4 = *(const float4*)(vp + (size_t)n * CH + c4);
        Ks[nl][c4 + 0] = __expf(k4.x - maxc[c4 + 0]) * invc[c4 + 0];
        Ks[nl][c4 + 1] = __expf(k4.y - maxc[c4 + 1]) * invc[c4 + 1];
        Ks[nl][c4 + 2] = __expf(k4.z - maxc[c4 + 2]) * invc[c4 + 2];
        Ks[nl][c4 + 3] = __expf(k4.w - maxc[c4 + 3]) * invc[c4 + 3];
        Vs[nl][c4 + 0] = v4.x; Vs[nl][c4 + 1] = v4.y;
        Vs[nl][c4 + 2] = v4.z; Vs[nl][c4 + 3] = v4.w;
      } else {
        Ks[nl][c4 + 0] = 0.f; Ks[nl][c4 + 1] = 0.f;
        Ks[nl][c4 + 2] = 0.f; Ks[nl][c4 + 3] = 0.f;
        Vs[nl][c4 + 0] = 0.f; Vs[nl][c4 + 1] = 0.f;
        Vs[nl][c4 + 2] = 0.f; Vs[nl][c4 + 3] = 0.f;
      }
    }
    __syncthreads();
#pragma unroll
    for (int nn = 0; nn < 32; ++nn) {
      const float4 a = *(const float4*)&Ks[nn][ty << 2];
      const float4 b = *(const float4*)&Vs[nn][tx << 2];
      const float av[4] = {a.x, a.y, a.z, a.w};
      const float bv[4] = {b.x, b.y, b.z, b.w};
#pragma unroll
      for (int i = 0; i < 4; ++i)
#pragma unroll
        for (int j = 0; j < 4; ++j) acc[i][j] = fmaf(av[i], bv[j], acc[i][j]);
    }
    __syncthreads();
  }
#pragma unroll
  for (int i = 0; i < 4; ++i)
#pragma unroll
    for (int j = 0; j < 4; ++j) {
      const int cc = (ty << 2) + i, dd = (tx << 2) + j;
      kvout[((size_t)bh * 64 + cc) * 64 + dd] = acc[i][j];
    }
}

// ---------------------------------------------------------------------------
// Depthwise conv KSxKS on v_img (spatial 28x28, channels = heads*64),
// layout (B, NH, N, CH) with spatial index n-1. Output (B, NH, HW, CH).
// ---------------------------------------------------------------------------
template <int KS>
__global__ __launch_bounds__(256) void dwconv_kernel(const float* __restrict__ v,
                                                     const float* __restrict__ w,
                                                     const float* __restrict__ bias,
                                                     float* __restrict__ out,
                                                     int head0, int nh) {
  const int bx = blockIdx.x;
  const int b = bx / nh, hl = bx % nh;
  const int head = head0 + hl;
  const int t = threadIdx.x;
  const int c = t & 63, slot = t >> 6;
  const int chl = hl * 64 + c;
  const float* wp = w + (size_t)chl * KS * KS;
  float wr[KS * KS];
#pragma unroll
  for (int i = 0; i < KS * KS; ++i) wr[i] = wp[i];
  const float bv = bias[chl];
  const float* vp = v + ((size_t)(b * NH + head) * N_ + 1) * CH;
  float* op = out + (size_t)(b * NH + head) * HW_ * CH;
  constexpr int P = KS / 2;
  for (int pos = blockIdx.y * 4 + slot; pos < HW_; pos += 16) {
    const int y = pos / 28, x = pos - y * 28;
    float acc = bv;
#pragma unroll
    for (int dy = 0; dy < KS; ++dy) {
      const int yy = y + dy - P;
      if (yy < 0 || yy >= 28) continue;
#pragma unroll
      for (int dx = 0; dx < KS; ++dx) {
        const int xx = x + dx - P;
        if (xx < 0 || xx >= 28) continue;
        acc = fmaf(wr[dy * KS + dx], vp[(size_t)(yy * 28 + xx) * CH + c], acc);
      }
    }
    op[(size_t)pos * CH + c] = acc;
  }
}

// ---------------------------------------------------------------------------
// att[b,n,head*64+d] = 0.125 * (q_row @ kv) + (n>0 ? q[n][d]*conv_v[n-1][d] : 0)
// ---------------------------------------------------------------------------
__global__ __launch_bounds__(256) void att_kernel(const float* __restrict__ q,
                                                  const float* __restrict__ kv,
                                                  const float* __restrict__ conv_v,
                                                  float* __restrict__ att) {
  const int bh = blockIdx.x;
  const int b = bh >> 3, head = bh & 7;
  const int n0 = blockIdx.y * 64;
  const int t = threadIdx.x;
  __shared__ float Qs[64][68];   // Qs[c][n_local]
  __shared__ float KVs[64][68];  // KVs[c][d]
  const float* qp = q + (size_t)bh * N_ * CH;
  {
    const int lr = t >> 2;
    const int n = n0 + lr;
#pragma unroll
    for (int ch = 0; ch < 4; ++ch) {
      const int lk = ((t & 3) << 2) + ch * 16;
      float4 a4 = make_float4(0.f, 0.f, 0.f, 0.f);
      if (n < N_) a4 = *(const float4*)(qp + (size_t)n * CH + lk);
      Qs[lk + 0][lr] = a4.x; Qs[lk + 1][lr] = a4.y;
      Qs[lk + 2][lr] = a4.z; Qs[lk + 3][lr] = a4.w;
    }
    const float* kvp = kv + (size_t)bh * 64 * 64;
#pragma unroll
    for (int ch = 0; ch < 4; ++ch) {
      const int lin = ch * 1024 + t * 4;
      const int cc = lin >> 6, dd = lin & 63;
      const float4 b4 = *(const float4*)(kvp + lin);
      *(float4*)&KVs[cc][dd] = b4;
    }
  }
  __syncthreads();
  const int tx = t & 15, ty = t >> 4;
  float acc[4][4] = {};
#pragma unroll 16
  for (int kk = 0; kk < 64; ++kk) {
    const float4 a = *(const float4*)&Qs[kk][ty << 2];
    const float4 bb = *(const float4*)&KVs[kk][tx << 2];
    const float av[4] = {a.x, a.y, a.z, a.w};
    const float bv[4] = {bb.x, bb.y, bb.z, bb.w};
#pragma unroll
    for (int i = 0; i < 4; ++i)
#pragma unroll
      for (int j = 0; j < 4; ++j) acc[i][j] = fmaf(av[i], bv[j], acc[i][j]);
  }
  const float* cvp = conv_v + (size_t)bh * HW_ * CH;
#pragma unroll
  for (int i = 0; i < 4; ++i) {
    const int nl = (ty << 2) + i, n = n0 + nl;
    if (n >= N_) break;
#pragma unroll
    for (int j = 0; j < 4; ++j) {
      const int d = (tx << 2) + j;
      float val = 0.125f * acc[i][j];
      if (n > 0) val = fmaf(Qs[d][nl], cvp[(size_t)(n - 1) * CH + d], val);
      att[((size_t)b * N_ + n) * C_ + head * CH + d] = val;
    }
  }
}

// ---------------------------------------------------------------------------
// Proj GEMM: out[m][j] = sum_k A[m][k]*W[j][k] + bias[j]; M=25120, N=512, K=512
// ---------------------------------------------------------------------------
__global__ __launch_bounds__(256) void gemm_proj(const float* __restrict__ A,
                                                 const float* __restrict__ W,
                                                 const float* __restrict__ bias,
                                                 float* __restrict__ out) {
  __shared__ float As[16][68];
  __shared__ float Bs[16][68];
  const int t = threadIdx.x;
  const int row0 = blockIdx.y * 64, col0 = blockIdx.x * 64;
  const int lr = t >> 2, lk = (t & 3) << 2;
  const int tx = t & 15, ty = t >> 4;
  float acc[4][4] = {};
  for (int k0 = 0; k0 < 512; k0 += 16) {
    float4 a4 = make_float4(0.f, 0.f, 0.f, 0.f);
    const int gr = row0 + lr;
    if (gr < M_) a4 = *(const float4*)(A + (size_t)gr * 512 + k0 + lk);
    As[lk + 0][lr] = a4.x; As[lk + 1][lr] = a4.y;
    As[lk + 2][lr] = a4.z; As[lk + 3][lr] = a4.w;
    const float4 b4 = *(const float4*)(W + (size_t)(col0 + lr) * 512 + k0 + lk);
    Bs[lk + 0][lr] = b4.x; Bs[lk + 1][lr] = b4.y;
    Bs[lk + 2][lr] = b4.z; Bs[lk + 3][lr] = b4.w;
    __syncthreads();
#pragma unroll
    for (int kk = 0; kk < 16; ++kk) {
      const float4 a = *(const float4*)&As[kk][ty << 2];
      const float4 b = *(const float4*)&Bs[kk][tx << 2];
      const float av[4] = {a.x, a.y, a.z, a.w};
      const float bv[4] = {b.x, b.y, b.z, b.w};
#pragma unroll
      for (int i = 0; i < 4; ++i)
#pragma unroll
        for (int j = 0; j < 4; ++j) acc[i][j] = fmaf(av[i], bv[j], acc[i][j]);
    }
    __syncthreads();
  }
#pragma unroll
  for (int i = 0; i < 4; ++i) {
    const int m = row0 + (ty << 2) + i;
    if (m >= M_) break;
#pragma unroll
    for (int j = 0; j < 4; ++j) {
      const int col = col0 + (tx << 2) + j;
      out[(size_t)m * 512 + col] = acc[i][j] + bias[col];
    }
  }
}

extern "C" void kernel_launch(void* const* d_in, const int* in_sizes, int n_in,
                              void* d_out, int out_size, void* d_ws, size_t ws_size,
                              hipStream_t stream) {
  const float* x      = (const float*)d_in[0];
  const float* qkv_w  = (const float*)d_in[3];
  const float* proj_w = (const float*)d_in[4];
  const float* proj_b = (const float*)d_in[5];
  const float* cw3    = (const float*)d_in[6];
  const float* cb3    = (const float*)d_in[7];
  const float* cw5    = (const float*)d_in[8];
  const float* cb5    = (const float*)d_in[9];
  const float* cw7    = (const float*)d_in[10];
  const float* cb7    = (const float*)d_in[11];
  float* out = (float*)d_out;
  float* ws = (float*)d_ws;

  const size_t SZ = (size_t)B_ * NH * N_ * CH;  // 12,861,440 floats
  float* q  = ws;
  float* k  = ws + SZ;
  float* v  = ws + 2 * SZ;
  float* kv = ws + 3 * SZ;           // 256*64*64 floats
  float* conv_v = k;                 // alias: k dead after kv_kernel
  float* att    = v;                 // alias: v dead after conv kernels

  gemm_qkv<<<dim3(24, 393), 256, 0, stream>>>(x, qkv_w, q, k, v);
  kv_kernel<<<dim3(256), 256, 0, stream>>>(k, v, kv);
  dwconv_kernel<3><<<dim3(64, 4), 256, 0, stream>>>(v, cw3, cb3, conv_v, 0, 2);
  dwconv_kernel<5><<<dim3(96, 4), 256, 0, stream>>>(v, cw5, cb5, conv_v, 2, 3);
  dwconv_kernel<7><<<dim3(96, 4), 256, 0, stream>>>(v, cw7, cb7, conv_v, 5, 3);
  att_kernel<<<dim3(256, 13), 256, 0, stream>>>(q, kv, conv_v, att);
  gemm_proj<<<dim3(8, 393), 256, 0, stream>>>(att, proj_w, proj_b, out);
}

// Round 2
// 920.614 us; speedup vs baseline: 1.6278x; 1.6278x over previous
//
#include <hip/hip_runtime.h>
#include <hip/hip_bf16.h>

#define B_ 32
#define N_ 785
#define C_ 512
#define NH 8
#define CH 64
#define HW_ 784
#define M_ (B_ * N_)  // 25120

typedef __attribute__((ext_vector_type(8))) short short8v;
typedef __attribute__((ext_vector_type(4))) float f32x4;

__device__ inline void gload_lds16(const void* g, void* l) {
  __builtin_amdgcn_global_load_lds(
      (const __attribute__((address_space(1))) unsigned int*)g,
      (__attribute__((address_space(3))) unsigned int*)l, 16, 0, 0);
}

// ---------------------------------------------------------------------------
// fp32 -> bf16 cast, 8 elems/thread
// ---------------------------------------------------------------------------
__global__ __launch_bounds__(256) void cast_bf16(const float* __restrict__ in,
                                                 __hip_bfloat16* __restrict__ out,
                                                 int n8) {
  int i = blockIdx.x * 256 + threadIdx.x;
  const int stride = gridDim.x * 256;
  for (; i < n8; i += stride) {
    const float4 a = ((const float4*)in)[(size_t)i * 2];
    const float4 b = ((const float4*)in)[(size_t)i * 2 + 1];
    union { __hip_bfloat16 h[8]; short8v v; } u;
    u.h[0] = __float2bfloat16(a.x); u.h[1] = __float2bfloat16(a.y);
    u.h[2] = __float2bfloat16(a.z); u.h[3] = __float2bfloat16(a.w);
    u.h[4] = __float2bfloat16(b.x); u.h[5] = __float2bfloat16(b.y);
    u.h[6] = __float2bfloat16(b.z); u.h[7] = __float2bfloat16(b.w);
    ((short8v*)out)[i] = u.v;
  }
}

// ---------------------------------------------------------------------------
// MFMA GEMM (m97 structure): C[m][n] = sum_k A[m][k] * W[n][k]
// 128x128 tile, BK=32, 4 waves (2x2, each 64x64), mfma_f32_16x16x32_bf16.
// A: [M][512] bf16 (row-clamped), W: [NCOLS][512] bf16.
// QKV epilogue scatters into q/k/v (B,NH,N,CH) fp32.
// ---------------------------------------------------------------------------
__global__ __launch_bounds__(256) void gemm_qkv_mfma(const __hip_bfloat16* __restrict__ A,
                                                     const __hip_bfloat16* __restrict__ W,
                                                     float* __restrict__ q,
                                                     float* __restrict__ k,
                                                     float* __restrict__ v) {
  __shared__ short As[128 * 32];
  __shared__ short Bs[128 * 32];
  const int t = threadIdx.x;
  const int w = t >> 6, l = t & 63;
  const int row0 = blockIdx.y * 128, col0 = blockIdx.x * 128;
  const int rw0 = (w >> 1) * 64, cw0 = (w & 1) * 64;
  f32x4 acc[4][4] = {};

  const int aoff = (rw0 + (l & 15)) * 32 + (l >> 4) * 8;
  const int boff = (cw0 + (l & 15)) * 32 + (l >> 4) * 8;

  for (int k0 = 0; k0 < 512; k0 += 32) {
#pragma unroll
    for (int it = 0; it < 2; ++it) {
      const int chunk = it * 256 + t;          // 16B chunk id, 512 per tile
      const int r = chunk >> 2, kc = chunk & 3;
      const int ra = (row0 + r < M_) ? (row0 + r) : (M_ - 1);
      gload_lds16(A + (size_t)ra * 512 + k0 + kc * 8,
                  (char*)As + it * 4096 + w * 1024);
      gload_lds16(W + (size_t)(col0 + r) * 512 + k0 + kc * 8,
                  (char*)Bs + it * 4096 + w * 1024);
    }
    __syncthreads();
    short8v af[4], bf[4];
#pragma unroll
    for (int i = 0; i < 4; ++i) af[i] = *(const short8v*)&As[aoff + i * 16 * 32];
#pragma unroll
    for (int j = 0; j < 4; ++j) bf[j] = *(const short8v*)&Bs[boff + j * 16 * 32];
#pragma unroll
    for (int i = 0; i < 4; ++i)
#pragma unroll
      for (int j = 0; j < 4; ++j)
        acc[i][j] = __builtin_amdgcn_mfma_f32_16x16x32_bf16(af[i], bf[j], acc[i][j], 0, 0, 0);
    __syncthreads();
  }

#pragma unroll
  for (int i = 0; i < 4; ++i)
#pragma unroll
    for (int j = 0; j < 4; ++j) {
      const int colg = col0 + cw0 + j * 16 + (l & 15);
      const int ts = colg >> 9, head = (colg >> 6) & 7, c = colg & 63;
      float* dst = (ts == 0) ? q : ((ts == 1) ? k : v);
#pragma unroll
      for (int r = 0; r < 4; ++r) {
        const int m = row0 + rw0 + i * 16 + ((l >> 4) << 2) + r;
        if (m < M_) {
          const int bb = m / N_, n = m - bb * N_;
          dst[(((size_t)bb * NH + head) * N_ + n) * CH + c] = acc[i][j][r];
        }
      }
    }
}

__global__ __launch_bounds__(256) void gemm_proj_mfma(const __hip_bfloat16* __restrict__ A,
                                                      const __hip_bfloat16* __restrict__ W,
                                                      const float* __restrict__ bias,
                                                      float* __restrict__ out) {
  __shared__ short As[128 * 32];
  __shared__ short Bs[128 * 32];
  const int t = threadIdx.x;
  const int w = t >> 6, l = t & 63;
  const int row0 = blockIdx.y * 128, col0 = blockIdx.x * 128;
  const int rw0 = (w >> 1) * 64, cw0 = (w & 1) * 64;
  f32x4 acc[4][4] = {};

  const int aoff = (rw0 + (l & 15)) * 32 + (l >> 4) * 8;
  const int boff = (cw0 + (l & 15)) * 32 + (l >> 4) * 8;

  for (int k0 = 0; k0 < 512; k0 += 32) {
#pragma unroll
    for (int it = 0; it < 2; ++it) {
      const int chunk = it * 256 + t;
      const int r = chunk >> 2, kc = chunk & 3;
      const int ra = (row0 + r < M_) ? (row0 + r) : (M_ - 1);
      gload_lds16(A + (size_t)ra * 512 + k0 + kc * 8,
                  (char*)As + it * 4096 + w * 1024);
      gload_lds16(W + (size_t)(col0 + r) * 512 + k0 + kc * 8,
                  (char*)Bs + it * 4096 + w * 1024);
    }
    __syncthreads();
    short8v af[4], bf[4];
#pragma unroll
    for (int i = 0; i < 4; ++i) af[i] = *(const short8v*)&As[aoff + i * 16 * 32];
#pragma unroll
    for (int j = 0; j < 4; ++j) bf[j] = *(const short8v*)&Bs[boff + j * 16 * 32];
#pragma unroll
    for (int i = 0; i < 4; ++i)
#pragma unroll
      for (int j = 0; j < 4; ++j)
        acc[i][j] = __builtin_amdgcn_mfma_f32_16x16x32_bf16(af[i], bf[j], acc[i][j], 0, 0, 0);
    __syncthreads();
  }

#pragma unroll
  for (int i = 0; i < 4; ++i)
#pragma unroll
    for (int j = 0; j < 4; ++j) {
      const int colg = col0 + cw0 + j * 16 + (l & 15);
      const float bv = bias[colg];
#pragma unroll
      for (int r = 0; r < 4; ++r) {
        const int m = row0 + rw0 + i * 16 + ((l >> 4) << 2) + r;
        if (m < M_) out[(size_t)m * 512 + colg] = acc[i][j][r] + bv;
      }
    }
}

// ---------------------------------------------------------------------------
// Per (b,h): softmax over N per channel of k (online), then
// kv[c][d] = sum_n softmax(k)[n][c] * v[n][d]   (64x64, K=785)
// ---------------------------------------------------------------------------
__global__ __launch_bounds__(256) void kv_kernel(const float* __restrict__ k,
                                                 const float* __restrict__ v,
                                                 float* __restrict__ kvout) {
  const int bh = blockIdx.x;
  const float* kp = k + (size_t)bh * N_ * CH;
  const float* vp = v + (size_t)bh * N_ * CH;
  const int t = threadIdx.x;
  const int c = t & 63, g = t >> 6;
  __shared__ float smax[4][64], ssum[4][64];
  __shared__ float maxc[64], invc[64];
  float m = -1e30f, s = 0.f;
  for (int n = g; n < N_; n += 4) {
    const float x = kp[(size_t)n * CH + c];
    const float mn = fmaxf(m, x);
    s = s * __expf(m - mn) + __expf(x - mn);
    m = mn;
  }
  smax[g][c] = m; ssum[g][c] = s;
  __syncthreads();
  if (t < 64) {
    float mm = smax[0][t];
#pragma unroll
    for (int i = 1; i < 4; ++i) mm = fmaxf(mm, smax[i][t]);
    float ss = 0.f;
#pragma unroll
    for (int i = 0; i < 4; ++i) ss += ssum[i][t] * __expf(smax[i][t] - mm);
    maxc[t] = mm; invc[t] = 1.f / ss;
  }
  __syncthreads();
  __shared__ float Ks[32][68];
  __shared__ float Vs[32][68];
  const int tx = t & 15, ty = t >> 4;
  float acc[4][4] = {};
  for (int n0 = 0; n0 < N_; n0 += 32) {
#pragma unroll
    for (int half = 0; half < 2; ++half) {
      const int lin = half * 1024 + t * 4;
      const int nl = lin >> 6, c4 = lin & 63;
      const int n = n0 + nl;
      if (n < N_) {
        const float4 k4 = *(const float4*)(kp + (size_t)n * CH + c4);
        const float4 v4 = *(const float4*)(vp + (size_t)n * CH + c4);
        Ks[nl][c4 + 0] = __expf(k4.x - maxc[c4 + 0]) * invc[c4 + 0];
        Ks[nl][c4 + 1] = __expf(k4.y - maxc[c4 + 1]) * invc[c4 + 1];
        Ks[nl][c4 + 2] = __expf(k4.z - maxc[c4 + 2]) * invc[c4 + 2];
        Ks[nl][c4 + 3] = __expf(k4.w - maxc[c4 + 3]) * invc[c4 + 3];
        Vs[nl][c4 + 0] = v4.x; Vs[nl][c4 + 1] = v4.y;
        Vs[nl][c4 + 2] = v4.z; Vs[nl][c4 + 3] = v4.w;
      } else {
        Ks[nl][c4 + 0] = 0.f; Ks[nl][c4 + 1] = 0.f;
        Ks[nl][c4 + 2] = 0.f; Ks[nl][c4 + 3] = 0.f;
        Vs[nl][c4 + 0] = 0.f; Vs[nl][c4 + 1] = 0.f;
        Vs[nl][c4 + 2] = 0.f; Vs[nl][c4 + 3] = 0.f;
      }
    }
    __syncthreads();
#pragma unroll
    for (int nn = 0; nn < 32; ++nn) {
      const float4 a = *(const float4*)&Ks[nn][ty << 2];
      const float4 b = *(const float4*)&Vs[nn][tx << 2];
      const float av[4] = {a.x, a.y, a.z, a.w};
      const float bv[4] = {b.x, b.y, b.z, b.w};
#pragma unroll
      for (int i = 0; i < 4; ++i)
#pragma unroll
        for (int j = 0; j < 4; ++j) acc[i][j] = fmaf(av[i], bv[j], acc[i][j]);
    }
    __syncthreads();
  }
#pragma unroll
  for (int i = 0; i < 4; ++i)
#pragma unroll
    for (int j = 0; j < 4; ++j) {
      const int cc = (ty << 2) + i, dd = (tx << 2) + j;
      kvout[((size_t)bh * 64 + cc) * 64 + dd] = acc[i][j];
    }
}

// ---------------------------------------------------------------------------
// Depthwise conv KSxKS on v_img (28x28), layout (B,NH,N,CH), out (B,NH,HW,CH)
// ---------------------------------------------------------------------------
template <int KS>
__global__ __launch_bounds__(256) void dwconv_kernel(const float* __restrict__ v,
                                                     const float* __restrict__ w,
                                                     const float* __restrict__ bias,
                                                     float* __restrict__ out,
                                                     int head0, int nh) {
  const int bx = blockIdx.x;
  const int b = bx / nh, hl = bx % nh;
  const int head = head0 + hl;
  const int t = threadIdx.x;
  const int c = t & 63, slot = t >> 6;
  const int chl = hl * 64 + c;
  const float* wp = w + (size_t)chl * KS * KS;
  float wr[KS * KS];
#pragma unroll
  for (int i = 0; i < KS * KS; ++i) wr[i] = wp[i];
  const float bv = bias[chl];
  const float* vp = v + ((size_t)(b * NH + head) * N_ + 1) * CH;
  float* op = out + (size_t)(b * NH + head) * HW_ * CH;
  constexpr int P = KS / 2;
  for (int pos = blockIdx.y * 4 + slot; pos < HW_; pos += 16) {
    const int y = pos / 28, x = pos - y * 28;
    float acc = bv;
#pragma unroll
    for (int dy = 0; dy < KS; ++dy) {
      const int yy = y + dy - P;
      if (yy < 0 || yy >= 28) continue;
#pragma unroll
      for (int dx = 0; dx < KS; ++dx) {
        const int xx = x + dx - P;
        if (xx < 0 || xx >= 28) continue;
        acc = fmaf(wr[dy * KS + dx], vp[(size_t)(yy * 28 + xx) * CH + c], acc);
      }
    }
    op[(size_t)pos * CH + c] = acc;
  }
}

// ---------------------------------------------------------------------------
// att[b,n,head*64+d] (bf16) = 0.125*(q@kv) + (n>0 ? q[n][d]*conv_v[n-1][d] : 0)
// ---------------------------------------------------------------------------
__global__ __launch_bounds__(256) void att_kernel(const float* __restrict__ q,
                                                  const float* __restrict__ kv,
                                                  const float* __restrict__ conv_v,
                                                  __hip_bfloat16* __restrict__ att) {
  const int bh = blockIdx.x;
  const int b = bh >> 3, head = bh & 7;
  const int n0 = blockIdx.y * 64;
  const int t = threadIdx.x;
  __shared__ float Qs[64][68];
  __shared__ float KVs[64][68];
  const float* qp = q + (size_t)bh * N_ * CH;
  {
    const int lr = t >> 2;
    const int n = n0 + lr;
#pragma unroll
    for (int ch = 0; ch < 4; ++ch) {
      const int lk = ((t & 3) << 2) + ch * 16;
      float4 a4 = make_float4(0.f, 0.f, 0.f, 0.f);
      if (n < N_) a4 = *(const float4*)(qp + (size_t)n * CH + lk);
      Qs[lk + 0][lr] = a4.x; Qs[lk + 1][lr] = a4.y;
      Qs[lk + 2][lr] = a4.z; Qs[lk + 3][lr] = a4.w;
    }
    const float* kvp = kv + (size_t)bh * 64 * 64;
#pragma unroll
    for (int ch = 0; ch < 4; ++ch) {
      const int lin = ch * 1024 + t * 4;
      const int cc = lin >> 6, dd = lin & 63;
      const float4 b4 = *(const float4*)(kvp + lin);
      *(float4*)&KVs[cc][dd] = b4;
    }
  }
  __syncthreads();
  const int tx = t & 15, ty = t >> 4;
  float acc[4][4] = {};
#pragma unroll 16
  for (int kk = 0; kk < 64; ++kk) {
    const float4 a = *(const float4*)&Qs[kk][ty << 2];
    const float4 bb = *(const float4*)&KVs[kk][tx << 2];
    const float av[4] = {a.x, a.y, a.z, a.w};
    const float bv[4] = {bb.x, bb.y, bb.z, bb.w};
#pragma unroll
    for (int i = 0; i < 4; ++i)
#pragma unroll
      for (int j = 0; j < 4; ++j) acc[i][j] = fmaf(av[i], bv[j], acc[i][j]);
  }
  const float* cvp = conv_v + (size_t)bh * HW_ * CH;
#pragma unroll
  for (int i = 0; i < 4; ++i) {
    const int nl = (ty << 2) + i, n = n0 + nl;
    if (n >= N_) break;
#pragma unroll
    for (int j = 0; j < 4; ++j) {
      const int d = (tx << 2) + j;
      float val = 0.125f * acc[i][j];
      if (n > 0) val = fmaf(Qs[d][nl], cvp[(size_t)(n - 1) * CH + d], val);
      att[((size_t)b * N_ + n) * C_ + head * CH + d] = __float2bfloat16(val);
    }
  }
}

extern "C" void kernel_launch(void* const* d_in, const int* in_sizes, int n_in,
                              void* d_out, int out_size, void* d_ws, size_t ws_size,
                              hipStream_t stream) {
  const float* x      = (const float*)d_in[0];
  const float* qkv_w  = (const float*)d_in[3];
  const float* proj_w = (const float*)d_in[4];
  const float* proj_b = (const float*)d_in[5];
  const float* cw3    = (const float*)d_in[6];
  const float* cb3    = (const float*)d_in[7];
  const float* cw5    = (const float*)d_in[8];
  const float* cb5    = (const float*)d_in[9];
  const float* cw7    = (const float*)d_in[10];
  const float* cb7    = (const float*)d_in[11];
  float* out = (float*)d_out;
  float* ws = (float*)d_ws;

  const size_t SZ = (size_t)B_ * NH * N_ * CH;  // 12,861,440 floats
  float* q  = ws;
  float* k  = ws + SZ;
  float* v  = ws + 2 * SZ;
  float* kv = ws + 3 * SZ;                       // 256*64*64 floats
  __hip_bfloat16* xb     = (__hip_bfloat16*)(ws + 3 * SZ + 256 * 64 * 64);
  __hip_bfloat16* qkvwb  = xb + SZ;              // 786432 bf16
  __hip_bfloat16* projwb = qkvwb + 786432;       // 262144 bf16
  float* conv_v = k;                             // alias: k dead after kv_kernel
  __hip_bfloat16* attb = (__hip_bfloat16*)v;     // alias: v dead after dwconv

  cast_bf16<<<2048, 256, 0, stream>>>(x, xb, (int)(SZ / 8));
  cast_bf16<<<384, 256, 0, stream>>>(qkv_w, qkvwb, 786432 / 8);
  cast_bf16<<<128, 256, 0, stream>>>(proj_w, projwb, 262144 / 8);

  gemm_qkv_mfma<<<dim3(12, 197), 256, 0, stream>>>(xb, qkvwb, q, k, v);
  kv_kernel<<<dim3(256), 256, 0, stream>>>(k, v, kv);
  dwconv_kernel<3><<<dim3(64, 4), 256, 0, stream>>>(v, cw3, cb3, conv_v, 0, 2);
  dwconv_kernel<5><<<dim3(96, 4), 256, 0, stream>>>(v, cw5, cb5, conv_v, 2, 3);
  dwconv_kernel<7><<<dim3(96, 4), 256, 0, stream>>>(v, cw7, cb7, conv_v, 5, 3);
  att_kernel<<<dim3(256, 13), 256, 0, stream>>>(q, kv, conv_v, attb);
  gemm_proj_mfma<<<dim3(4, 197), 256, 0, stream>>>(attb, projwb, proj_b, out);
}

// Round 5
// 620.656 us; speedup vs baseline: 2.4145x; 1.4833x over previous
//
#include <hip/hip_runtime.h>
#include <hip/hip_bf16.h>

#define B_ 32
#define N_ 785
#define C_ 512
#define NH 8
#define CH 64
#define HW_ 784
#define M_ (B_ * N_)  // 25120

typedef __attribute__((ext_vector_type(8))) short short8v;
typedef __attribute__((ext_vector_type(4))) float f32x4;

__device__ inline void gload_lds16(const void* g, void* l) {
  __builtin_amdgcn_global_load_lds(
      (const __attribute__((address_space(1))) unsigned int*)g,
      (__attribute__((address_space(3))) unsigned int*)l, 16, 0, 0);
}

// ---------------------------------------------------------------------------
// fp32 -> bf16 cast, 8 elems/thread
// ---------------------------------------------------------------------------
__global__ __launch_bounds__(256) void cast_bf16(const float* __restrict__ in,
                                                 __hip_bfloat16* __restrict__ out,
                                                 int n8) {
  int i = blockIdx.x * 256 + threadIdx.x;
  const int stride = gridDim.x * 256;
  for (; i < n8; i += stride) {
    const float4 a = ((const float4*)in)[(size_t)i * 2];
    const float4 b = ((const float4*)in)[(size_t)i * 2 + 1];
    union { __hip_bfloat16 h[8]; short8v v; } u;
    u.h[0] = __float2bfloat16(a.x); u.h[1] = __float2bfloat16(a.y);
    u.h[2] = __float2bfloat16(a.z); u.h[3] = __float2bfloat16(a.w);
    u.h[4] = __float2bfloat16(b.x); u.h[5] = __float2bfloat16(b.y);
    u.h[6] = __float2bfloat16(b.z); u.h[7] = __float2bfloat16(b.w);
    ((short8v*)out)[i] = u.v;
  }
}

// ---------------------------------------------------------------------------
// Transpose dwconv weights to [k2][chl] so lane loads coalesce.
// wt3: 9 x 128, wt5: 25 x 192, wt7: 49 x 192
// ---------------------------------------------------------------------------
__global__ __launch_bounds__(256) void prep_weights(const float* __restrict__ cw3,
                                                    const float* __restrict__ cw5,
                                                    const float* __restrict__ cw7,
                                                    float* __restrict__ wt3,
                                                    float* __restrict__ wt5,
                                                    float* __restrict__ wt7) {
  const int i = blockIdx.x * 256 + threadIdx.x;
  if (i < 9 * 128) {
    const int idx = i >> 7, chl = i & 127;
    wt3[i] = cw3[chl * 9 + idx];
  }
  if (i < 25 * 192) {
    const int idx = i / 192, chl = i - idx * 192;
    wt5[i] = cw5[chl * 25 + idx];
  }
  if (i < 49 * 192) {
    const int idx = i / 192, chl = i - idx * 192;
    wt7[i] = cw7[chl * 49 + idx];
  }
}

// ---------------------------------------------------------------------------
// MFMA GEMM (m97 structure): C[m][n] = sum_k A[m][k] * W[n][k]
// ---------------------------------------------------------------------------
__global__ __launch_bounds__(256) void gemm_qkv_mfma(const __hip_bfloat16* __restrict__ A,
                                                     const __hip_bfloat16* __restrict__ W,
                                                     float* __restrict__ q,
                                                     float* __restrict__ k,
                                                     float* __restrict__ v) {
  __shared__ short As[128 * 32];
  __shared__ short Bs[128 * 32];
  const int t = threadIdx.x;
  const int w = t >> 6, l = t & 63;
  const int row0 = blockIdx.y * 128, col0 = blockIdx.x * 128;
  const int rw0 = (w >> 1) * 64, cw0 = (w & 1) * 64;
  f32x4 acc[4][4] = {};

  const int aoff = (rw0 + (l & 15)) * 32 + (l >> 4) * 8;
  const int boff = (cw0 + (l & 15)) * 32 + (l >> 4) * 8;

  for (int k0 = 0; k0 < 512; k0 += 32) {
#pragma unroll
    for (int it = 0; it < 2; ++it) {
      const int chunk = it * 256 + t;
      const int r = chunk >> 2, kc = chunk & 3;
      const int ra = (row0 + r < M_) ? (row0 + r) : (M_ - 1);
      gload_lds16(A + (size_t)ra * 512 + k0 + kc * 8,
                  (char*)As + it * 4096 + w * 1024);
      gload_lds16(W + (size_t)(col0 + r) * 512 + k0 + kc * 8,
                  (char*)Bs + it * 4096 + w * 1024);
    }
    __syncthreads();
    short8v af[4], bf[4];
#pragma unroll
    for (int i = 0; i < 4; ++i) af[i] = *(const short8v*)&As[aoff + i * 16 * 32];
#pragma unroll
    for (int j = 0; j < 4; ++j) bf[j] = *(const short8v*)&Bs[boff + j * 16 * 32];
#pragma unroll
    for (int i = 0; i < 4; ++i)
#pragma unroll
      for (int j = 0; j < 4; ++j)
        acc[i][j] = __builtin_amdgcn_mfma_f32_16x16x32_bf16(af[i], bf[j], acc[i][j], 0, 0, 0);
    __syncthreads();
  }

#pragma unroll
  for (int i = 0; i < 4; ++i)
#pragma unroll
    for (int j = 0; j < 4; ++j) {
      const int colg = col0 + cw0 + j * 16 + (l & 15);
      const int ts = colg >> 9, head = (colg >> 6) & 7, c = colg & 63;
      float* dst = (ts == 0) ? q : ((ts == 1) ? k : v);
#pragma unroll
      for (int r = 0; r < 4; ++r) {
        const int m = row0 + rw0 + i * 16 + ((l >> 4) << 2) + r;
        if (m < M_) {
          const int bb = m / N_, n = m - bb * N_;
          dst[(((size_t)bb * NH + head) * N_ + n) * CH + c] = acc[i][j][r];
        }
      }
    }
}

__global__ __launch_bounds__(256) void gemm_proj_mfma(const __hip_bfloat16* __restrict__ A,
                                                      const __hip_bfloat16* __restrict__ W,
                                                      const float* __restrict__ bias,
                                                      float* __restrict__ out) {
  __shared__ short As[128 * 32];
  __shared__ short Bs[128 * 32];
  const int t = threadIdx.x;
  const int w = t >> 6, l = t & 63;
  const int row0 = blockIdx.y * 128, col0 = blockIdx.x * 128;
  const int rw0 = (w >> 1) * 64, cw0 = (w & 1) * 64;
  f32x4 acc[4][4] = {};

  const int aoff = (rw0 + (l & 15)) * 32 + (l >> 4) * 8;
  const int boff = (cw0 + (l & 15)) * 32 + (l >> 4) * 8;

  for (int k0 = 0; k0 < 512; k0 += 32) {
#pragma unroll
    for (int it = 0; it < 2; ++it) {
      const int chunk = it * 256 + t;
      const int r = chunk >> 2, kc = chunk & 3;
      const int ra = (row0 + r < M_) ? (row0 + r) : (M_ - 1);
      gload_lds16(A + (size_t)ra * 512 + k0 + kc * 8,
                  (char*)As + it * 4096 + w * 1024);
      gload_lds16(W + (size_t)(col0 + r) * 512 + k0 + kc * 8,
                  (char*)Bs + it * 4096 + w * 1024);
    }
    __syncthreads();
    short8v af[4], bf[4];
#pragma unroll
    for (int i = 0; i < 4; ++i) af[i] = *(const short8v*)&As[aoff + i * 16 * 32];
#pragma unroll
    for (int j = 0; j < 4; ++j) bf[j] = *(const short8v*)&Bs[boff + j * 16 * 32];
#pragma unroll
    for (int i = 0; i < 4; ++i)
#pragma unroll
      for (int j = 0; j < 4; ++j)
        acc[i][j] = __builtin_amdgcn_mfma_f32_16x16x32_bf16(af[i], bf[j], acc[i][j], 0, 0, 0);
    __syncthreads();
  }

#pragma unroll
  for (int i = 0; i < 4; ++i)
#pragma unroll
    for (int j = 0; j < 4; ++j) {
      const int colg = col0 + cw0 + j * 16 + (l & 15);
      const float bv = bias[colg];
#pragma unroll
      for (int r = 0; r < 4; ++r) {
        const int m = row0 + rw0 + i * 16 + ((l >> 4) << 2) + r;
        if (m < M_) out[(size_t)m * 512 + colg] = acc[i][j][r] + bv;
      }
    }
}

// ---------------------------------------------------------------------------
// kv: per (b,h) softmax over N per channel of k, then kv[c][d]
// 1024 threads: 16 stat groups; GEMM 64x64 with 2x2 per thread.
// ---------------------------------------------------------------------------
__global__ __launch_bounds__(1024) void kv_kernel(const float* __restrict__ k,
                                                  const float* __restrict__ v,
                                                  float* __restrict__ kvout) {
  const int bh = blockIdx.x;
  const float* kp = k + (size_t)bh * N_ * CH;
  const float* vp = v + (size_t)bh * N_ * CH;
  const int t = threadIdx.x;
  const int c = t & 63, g = t >> 6;  // 16 groups
  __shared__ float smax[16][64], ssum[16][64];
  __shared__ float maxc[64], invc[64];
  float m = -1e30f, s = 0.f;
  for (int n = g; n < N_; n += 16) {
    const float xv = kp[(size_t)n * CH + c];
    const float mn = fmaxf(m, xv);
    s = s * __expf(m - mn) + __expf(xv - mn);
    m = mn;
  }
  smax[g][c] = m; ssum[g][c] = s;
  __syncthreads();
  if (t < 64) {
    float mm = smax[0][t];
#pragma unroll
    for (int i = 1; i < 16; ++i) mm = fmaxf(mm, smax[i][t]);
    float ss = 0.f;
#pragma unroll
    for (int i = 0; i < 16; ++i) ss += ssum[i][t] * __expf(smax[i][t] - mm);
    maxc[t] = mm; invc[t] = 1.f / ss;
  }
  __syncthreads();

  __shared__ float Ks[64][66];
  __shared__ float Vs[64][66];
  const int d0 = (t & 31) * 2, c0 = (t >> 5) * 2;
  const int nl = t >> 4, c4 = (t & 15) * 4;
  float a00 = 0.f, a01 = 0.f, a10 = 0.f, a11 = 0.f;
  for (int n0 = 0; n0 < N_; n0 += 64) {
    const int n = n0 + nl;
    if (n < N_) {
      const float4 k4 = *(const float4*)(kp + (size_t)n * CH + c4);
      const float4 v4 = *(const float4*)(vp + (size_t)n * CH + c4);
      Ks[nl][c4 + 0] = __expf(k4.x - maxc[c4 + 0]) * invc[c4 + 0];
      Ks[nl][c4 + 1] = __expf(k4.y - maxc[c4 + 1]) * invc[c4 + 1];
      Ks[nl][c4 + 2] = __expf(k4.z - maxc[c4 + 2]) * invc[c4 + 2];
      Ks[nl][c4 + 3] = __expf(k4.w - maxc[c4 + 3]) * invc[c4 + 3];
      Vs[nl][c4 + 0] = v4.x; Vs[nl][c4 + 1] = v4.y;
      Vs[nl][c4 + 2] = v4.z; Vs[nl][c4 + 3] = v4.w;
    } else {
      Ks[nl][c4 + 0] = 0.f; Ks[nl][c4 + 1] = 0.f;
      Ks[nl][c4 + 2] = 0.f; Ks[nl][c4 + 3] = 0.f;
      Vs[nl][c4 + 0] = 0.f; Vs[nl][c4 + 1] = 0.f;
      Vs[nl][c4 + 2] = 0.f; Vs[nl][c4 + 3] = 0.f;
    }
    __syncthreads();
#pragma unroll 16
    for (int nn = 0; nn < 64; ++nn) {
      const float2 kk = *(const float2*)&Ks[nn][c0];
      const float2 vv = *(const float2*)&Vs[nn][d0];
      a00 = fmaf(kk.x, vv.x, a00); a01 = fmaf(kk.x, vv.y, a01);
      a10 = fmaf(kk.y, vv.x, a10); a11 = fmaf(kk.y, vv.y, a11);
    }
    __syncthreads();
  }
  float* op = kvout + ((size_t)bh * 64 + c0) * 64 + d0;
  op[0] = a00; op[1] = a01;
  op[64] = a10; op[65] = a11;
}

// ---------------------------------------------------------------------------
// Fused depthwise conv: one output element per thread, grid (B*NH, 196).
// Per-wave-uniform position -> no divergence; weights pre-transposed.
// ---------------------------------------------------------------------------
template <int KS>
__device__ inline float conv_pt(const float* __restrict__ vp,
                                const float* __restrict__ wt, int wstride,
                                int chl, float bv, int y, int x, int c) {
  constexpr int P = KS / 2;
  float acc = bv;
#pragma unroll
  for (int dy = 0; dy < KS; ++dy) {
    const int yy = y + dy - P;
    if (yy < 0 || yy >= 28) continue;
#pragma unroll
    for (int dx = 0; dx < KS; ++dx) {
      const int xx = x + dx - P;
      if (xx < 0 || xx >= 28) continue;
      acc = fmaf(wt[(dy * KS + dx) * wstride + chl],
                 vp[(size_t)(yy * 28 + xx) * CH + c], acc);
    }
  }
  return acc;
}

__global__ __launch_bounds__(256) void dwconv_all(const float* __restrict__ v,
                                                  const float* __restrict__ wt3,
                                                  const float* __restrict__ cb3,
                                                  const float* __restrict__ wt5,
                                                  const float* __restrict__ cb5,
                                                  const float* __restrict__ wt7,
                                                  const float* __restrict__ cb7,
                                                  float* __restrict__ out) {
  const int bh = blockIdx.x;
  const int head = bh & 7;
  const int t = threadIdx.x;
  const int c = t & 63, slot = t >> 6;
  const int pos = blockIdx.y * 4 + slot;
  const int y = pos / 28, x = pos - y * 28;
  const float* vp = v + ((size_t)bh * N_ + 1) * CH;
  float r;
  if (head < 2) {
    const int chl = head * 64 + c;
    r = conv_pt<3>(vp, wt3, 128, chl, cb3[chl], y, x, c);
  } else if (head < 5) {
    const int chl = (head - 2) * 64 + c;
    r = conv_pt<5>(vp, wt5, 192, chl, cb5[chl], y, x, c);
  } else {
    const int chl = (head - 5) * 64 + c;
    r = conv_pt<7>(vp, wt7, 192, chl, cb7[chl], y, x, c);
  }
  out[((size_t)bh * HW_ + pos) * CH + c] = r;
}

// ---------------------------------------------------------------------------
// att (bf16) = 0.125*(q@kv) + (n>0 ? q[n][d]*conv_v[n-1][d] : 0)
// ---------------------------------------------------------------------------
__global__ __launch_bounds__(256) void att_kernel(const float* __restrict__ q,
                                                  const float* __restrict__ kv,
                                                  const float* __restrict__ conv_v,
                                                  __hip_bfloat16* __restrict__ att) {
  const int bh = blockIdx.x;
  const int b = bh >> 3, head = bh & 7;
  const int n0 = blockIdx.y * 64;
  const int t = threadIdx.x;
  __shared__ float Qs[64][68];
  __shared__ float KVs[64][68];
  const float* qp = q + (size_t)bh * N_ * CH;
  {
    const int lr = t >> 2;
    const int n = n0 + lr;
#pragma unroll
    for (int ch = 0; ch < 4; ++ch) {
      const int lk = ((t & 3) << 2) + ch * 16;
      float4 a4 = make_float4(0.f, 0.f, 0.f, 0.f);
      if (n < N_) a4 = *(const float4*)(qp + (size_t)n * CH + lk);
      Qs[lk + 0][lr] = a4.x; Qs[lk + 1][lr] = a4.y;
      Qs[lk + 2][lr] = a4.z; Qs[lk + 3][lr] = a4.w;
    }
    const float* kvp = kv + (size_t)bh * 64 * 64;
#pragma unroll
    for (int ch = 0; ch < 4; ++ch) {
      const int lin = ch * 1024 + t * 4;
      const int cc = lin >> 6, dd = lin & 63;
      const float4 b4 = *(const float4*)(kvp + lin);
      *(float4*)&KVs[cc][dd] = b4;
    }
  }
  __syncthreads();
  const int tx = t & 15, ty = t >> 4;
  float acc[4][4] = {};
#pragma unroll 16
  for (int kk = 0; kk < 64; ++kk) {
    const float4 a = *(const float4*)&Qs[kk][ty << 2];
    const float4 bb = *(const float4*)&KVs[kk][tx << 2];
    const float av[4] = {a.x, a.y, a.z, a.w};
    const float bv[4] = {bb.x, bb.y, bb.z, bb.w};
#pragma unroll
    for (int i = 0; i < 4; ++i)
#pragma unroll
      for (int j = 0; j < 4; ++j) acc[i][j] = fmaf(av[i], bv[j], acc[i][j]);
  }
  const float* cvp = conv_v + (size_t)bh * HW_ * CH;
#pragma unroll
  for (int i = 0; i < 4; ++i) {
    const int nl = (ty << 2) + i, n = n0 + nl;
    if (n >= N_) break;
#pragma unroll
    for (int j = 0; j < 4; ++j) {
      const int d = (tx << 2) + j;
      float val = 0.125f * acc[i][j];
      if (n > 0) val = fmaf(Qs[d][nl], cvp[(size_t)(n - 1) * CH + d], val);
      att[((size_t)b * N_ + n) * C_ + head * CH + d] = __float2bfloat16(val);
    }
  }
}

extern "C" void kernel_launch(void* const* d_in, const int* in_sizes, int n_in,
                              void* d_out, int out_size, void* d_ws, size_t ws_size,
                              hipStream_t stream) {
  const float* x      = (const float*)d_in[0];
  const float* qkv_w  = (const float*)d_in[3];
  const float* proj_w = (const float*)d_in[4];
  const float* proj_b = (const float*)d_in[5];
  const float* cw3    = (const float*)d_in[6];
  const float* cb3    = (const float*)d_in[7];
  const float* cw5    = (const float*)d_in[8];
  const float* cb5    = (const float*)d_in[9];
  const float* cw7    = (const float*)d_in[10];
  const float* cb7    = (const float*)d_in[11];
  float* out = (float*)d_out;
  float* ws = (float*)d_ws;

  const size_t SZ = (size_t)B_ * NH * N_ * CH;  // 12,861,440 floats
  float* q  = ws;
  float* k  = ws + SZ;
  float* v  = ws + 2 * SZ;
  float* kv = ws + 3 * SZ;                       // 256*64*64 floats
  __hip_bfloat16* xb     = (__hip_bfloat16*)(ws + 3 * SZ + 256 * 64 * 64);
  __hip_bfloat16* qkvwb  = xb + SZ;              // 786432 bf16
  __hip_bfloat16* projwb = qkvwb + 786432;       // 262144 bf16
  float* wt3 = (float*)(projwb + 262144);        // 1152
  float* wt5 = wt3 + 1152;                       // 4800
  float* wt7 = wt5 + 4800;                       // 9408
  float* conv_v = k;                             // alias: k dead after kv_kernel
  __hip_bfloat16* attb = (__hip_bfloat16*)v;     // alias: v dead after dwconv

  cast_bf16<<<2048, 256, 0, stream>>>(x, xb, (int)(SZ / 8));
  cast_bf16<<<384, 256, 0, stream>>>(qkv_w, qkvwb, 786432 / 8);
  cast_bf16<<<128, 256, 0, stream>>>(proj_w, projwb, 262144 / 8);
  prep_weights<<<48, 256, 0, stream>>>(cw3, cw5, cw7, wt3, wt5, wt7);

  gemm_qkv_mfma<<<dim3(12, 197), 256, 0, stream>>>(xb, qkvwb, q, k, v);
  kv_kernel<<<dim3(256), 1024, 0, stream>>>(k, v, kv);
  dwconv_all<<<dim3(256, 196), 256, 0, stream>>>(v, wt3, cb3, wt5, cb5, wt7, cb7, conv_v);
  att_kernel<<<dim3(256, 13), 256, 0, stream>>>(q, kv, conv_v, attb);
  gemm_proj_mfma<<<dim3(4, 197), 256, 0, stream>>>(attb, projwb, proj_b, out);
}

// Round 9
// 384.701 us; speedup vs baseline: 3.8955x; 1.6133x over previous
//
#include <hip/hip_runtime.h>
#include <hip/hip_bf16.h>

#define B_ 32
#define N_ 785
#define C_ 512
#define NH 8
#define CH 64
#define HW_ 784
#define M_ (B_ * N_)  // 25120

typedef __attribute__((ext_vector_type(8))) short short8v;
typedef __attribute__((ext_vector_type(4))) float f32x4;

__device__ inline void gload_lds16(const void* g, void* l) {
  __builtin_amdgcn_global_load_lds(
      (const __attribute__((address_space(1))) unsigned int*)g,
      (__attribute__((address_space(3))) unsigned int*)l, 16, 0, 0);
}

// ---------------------------------------------------------------------------
// fp32 -> bf16 cast, 8 elems/thread
// ---------------------------------------------------------------------------
__global__ __launch_bounds__(256) void cast_bf16(const float* __restrict__ in,
                                                 __hip_bfloat16* __restrict__ out,
                                                 int n8) {
  int i = blockIdx.x * 256 + threadIdx.x;
  const int stride = gridDim.x * 256;
  for (; i < n8; i += stride) {
    const float4 a = ((const float4*)in)[(size_t)i * 2];
    const float4 b = ((const float4*)in)[(size_t)i * 2 + 1];
    union { __hip_bfloat16 h[8]; short8v v; } u;
    u.h[0] = __float2bfloat16(a.x); u.h[1] = __float2bfloat16(a.y);
    u.h[2] = __float2bfloat16(a.z); u.h[3] = __float2bfloat16(a.w);
    u.h[4] = __float2bfloat16(b.x); u.h[5] = __float2bfloat16(b.y);
    u.h[6] = __float2bfloat16(b.z); u.h[7] = __float2bfloat16(b.w);
    ((short8v*)out)[i] = u.v;
  }
}

// ---------------------------------------------------------------------------
// Transpose dwconv weights to [k2][chl] so lane loads coalesce.
// wt3: 9 x 128, wt5: 25 x 192, wt7: 49 x 192
// ---------------------------------------------------------------------------
__global__ __launch_bounds__(256) void prep_weights(const float* __restrict__ cw3,
                                                    const float* __restrict__ cw5,
                                                    const float* __restrict__ cw7,
                                                    float* __restrict__ wt3,
                                                    float* __restrict__ wt5,
                                                    float* __restrict__ wt7) {
  const int i = blockIdx.x * 256 + threadIdx.x;
  if (i < 9 * 128) {
    const int idx = i >> 7, chl = i & 127;
    wt3[i] = cw3[chl * 9 + idx];
  }
  if (i < 25 * 192) {
    const int idx = i / 192, chl = i - idx * 192;
    wt5[i] = cw5[chl * 25 + idx];
  }
  if (i < 49 * 192) {
    const int idx = i / 192, chl = i - idx * 192;
    wt7[i] = cw7[chl * 49 + idx];
  }
}

// ---------------------------------------------------------------------------
// MFMA GEMM (m97 structure): C[m][n] = sum_k A[m][k] * W[n][k]
// ---------------------------------------------------------------------------
__global__ __launch_bounds__(256) void gemm_qkv_mfma(const __hip_bfloat16* __restrict__ A,
                                                     const __hip_bfloat16* __restrict__ W,
                                                     float* __restrict__ q,
                                                     float* __restrict__ k,
                                                     float* __restrict__ v) {
  __shared__ short As[128 * 32];
  __shared__ short Bs[128 * 32];
  const int t = threadIdx.x;
  const int w = t >> 6, l = t & 63;
  const int row0 = blockIdx.y * 128, col0 = blockIdx.x * 128;
  const int rw0 = (w >> 1) * 64, cw0 = (w & 1) * 64;
  f32x4 acc[4][4] = {};

  const int aoff = (rw0 + (l & 15)) * 32 + (l >> 4) * 8;
  const int boff = (cw0 + (l & 15)) * 32 + (l >> 4) * 8;

  for (int k0 = 0; k0 < 512; k0 += 32) {
#pragma unroll
    for (int it = 0; it < 2; ++it) {
      const int chunk = it * 256 + t;
      const int r = chunk >> 2, kc = chunk & 3;
      const int ra = (row0 + r < M_) ? (row0 + r) : (M_ - 1);
      gload_lds16(A + (size_t)ra * 512 + k0 + kc * 8,
                  (char*)As + it * 4096 + w * 1024);
      gload_lds16(W + (size_t)(col0 + r) * 512 + k0 + kc * 8,
                  (char*)Bs + it * 4096 + w * 1024);
    }
    __syncthreads();
    short8v af[4], bf[4];
#pragma unroll
    for (int i = 0; i < 4; ++i) af[i] = *(const short8v*)&As[aoff + i * 16 * 32];
#pragma unroll
    for (int j = 0; j < 4; ++j) bf[j] = *(const short8v*)&Bs[boff + j * 16 * 32];
#pragma unroll
    for (int i = 0; i < 4; ++i)
#pragma unroll
      for (int j = 0; j < 4; ++j)
        acc[i][j] = __builtin_amdgcn_mfma_f32_16x16x32_bf16(af[i], bf[j], acc[i][j], 0, 0, 0);
    __syncthreads();
  }

#pragma unroll
  for (int i = 0; i < 4; ++i)
#pragma unroll
    for (int j = 0; j < 4; ++j) {
      const int colg = col0 + cw0 + j * 16 + (l & 15);
      const int ts = colg >> 9, head = (colg >> 6) & 7, c = colg & 63;
      float* dst = (ts == 0) ? q : ((ts == 1) ? k : v);
#pragma unroll
      for (int r = 0; r < 4; ++r) {
        const int m = row0 + rw0 + i * 16 + ((l >> 4) << 2) + r;
        if (m < M_) {
          const int bb = m / N_, n = m - bb * N_;
          dst[(((size_t)bb * NH + head) * N_ + n) * CH + c] = acc[i][j][r];
        }
      }
    }
}

__global__ __launch_bounds__(256) void gemm_proj_mfma(const __hip_bfloat16* __restrict__ A,
                                                      const __hip_bfloat16* __restrict__ W,
                                                      const float* __restrict__ bias,
                                                      float* __restrict__ out) {
  __shared__ short As[128 * 32];
  __shared__ short Bs[128 * 32];
  const int t = threadIdx.x;
  const int w = t >> 6, l = t & 63;
  const int row0 = blockIdx.y * 128, col0 = blockIdx.x * 128;
  const int rw0 = (w >> 1) * 64, cw0 = (w & 1) * 64;
  f32x4 acc[4][4] = {};

  const int aoff = (rw0 + (l & 15)) * 32 + (l >> 4) * 8;
  const int boff = (cw0 + (l & 15)) * 32 + (l >> 4) * 8;

  for (int k0 = 0; k0 < 512; k0 += 32) {
#pragma unroll
    for (int it = 0; it < 2; ++it) {
      const int chunk = it * 256 + t;
      const int r = chunk >> 2, kc = chunk & 3;
      const int ra = (row0 + r < M_) ? (row0 + r) : (M_ - 1);
      gload_lds16(A + (size_t)ra * 512 + k0 + kc * 8,
                  (char*)As + it * 4096 + w * 1024);
      gload_lds16(W + (size_t)(col0 + r) * 512 + k0 + kc * 8,
                  (char*)Bs + it * 4096 + w * 1024);
    }
    __syncthreads();
    short8v af[4], bf[4];
#pragma unroll
    for (int i = 0; i < 4; ++i) af[i] = *(const short8v*)&As[aoff + i * 16 * 32];
#pragma unroll
    for (int j = 0; j < 4; ++j) bf[j] = *(const short8v*)&Bs[boff + j * 16 * 32];
#pragma unroll
    for (int i = 0; i < 4; ++i)
#pragma unroll
      for (int j = 0; j < 4; ++j)
        acc[i][j] = __builtin_amdgcn_mfma_f32_16x16x32_bf16(af[i], bf[j], acc[i][j], 0, 0, 0);
    __syncthreads();
  }

#pragma unroll
  for (int i = 0; i < 4; ++i)
#pragma unroll
    for (int j = 0; j < 4; ++j) {
      const int colg = col0 + cw0 + j * 16 + (l & 15);
      const float bv = bias[colg];
#pragma unroll
      for (int r = 0; r < 4; ++r) {
        const int m = row0 + rw0 + i * 16 + ((l >> 4) << 2) + r;
        if (m < M_) out[(size_t)m * 512 + colg] = acc[i][j][r] + bv;
      }
    }
}

// ---------------------------------------------------------------------------
// kv: per (b,h) softmax over N per channel of k, then kv[c][d]
// 1024 threads: 16 stat groups; GEMM 64x64 with 2x2 per thread.
// ---------------------------------------------------------------------------
__global__ __launch_bounds__(1024) void kv_kernel(const float* __restrict__ k,
                                                  const float* __restrict__ v,
                                                  float* __restrict__ kvout) {
  const int bh = blockIdx.x;
  const float* kp = k + (size_t)bh * N_ * CH;
  const float* vp = v + (size_t)bh * N_ * CH;
  const int t = threadIdx.x;
  const int c = t & 63, g = t >> 6;  // 16 groups
  __shared__ float smax[16][64], ssum[16][64];
  __shared__ float maxc[64], invc[64];
  float m = -1e30f, s = 0.f;
  for (int n = g; n < N_; n += 16) {
    const float xv = kp[(size_t)n * CH + c];
    const float mn = fmaxf(m, xv);
    s = s * __expf(m - mn) + __expf(xv - mn);
    m = mn;
  }
  smax[g][c] = m; ssum[g][c] = s;
  __syncthreads();
  if (t < 64) {
    float mm = smax[0][t];
#pragma unroll
    for (int i = 1; i < 16; ++i) mm = fmaxf(mm, smax[i][t]);
    float ss = 0.f;
#pragma unroll
    for (int i = 0; i < 16; ++i) ss += ssum[i][t] * __expf(smax[i][t] - mm);
    maxc[t] = mm; invc[t] = 1.f / ss;
  }
  __syncthreads();

  __shared__ float Ks[64][66];
  __shared__ float Vs[64][66];
  const int d0 = (t & 31) * 2, c0 = (t >> 5) * 2;
  const int nl = t >> 4, c4 = (t & 15) * 4;
  float a00 = 0.f, a01 = 0.f, a10 = 0.f, a11 = 0.f;
  for (int n0 = 0; n0 < N_; n0 += 64) {
    const int n = n0 + nl;
    if (n < N_) {
      const float4 k4 = *(const float4*)(kp + (size_t)n * CH + c4);
      const float4 v4 = *(const float4*)(vp + (size_t)n * CH + c4);
      Ks[nl][c4 + 0] = __expf(k4.x - maxc[c4 + 0]) * invc[c4 + 0];
      Ks[nl][c4 + 1] = __expf(k4.y - maxc[c4 + 1]) * invc[c4 + 1];
      Ks[nl][c4 + 2] = __expf(k4.z - maxc[c4 + 2]) * invc[c4 + 2];
      Ks[nl][c4 + 3] = __expf(k4.w - maxc[c4 + 3]) * invc[c4 + 3];
      Vs[nl][c4 + 0] = v4.x; Vs[nl][c4 + 1] = v4.y;
      Vs[nl][c4 + 2] = v4.z; Vs[nl][c4 + 3] = v4.w;
    } else {
      Ks[nl][c4 + 0] = 0.f; Ks[nl][c4 + 1] = 0.f;
      Ks[nl][c4 + 2] = 0.f; Ks[nl][c4 + 3] = 0.f;
      Vs[nl][c4 + 0] = 0.f; Vs[nl][c4 + 1] = 0.f;
      Vs[nl][c4 + 2] = 0.f; Vs[nl][c4 + 3] = 0.f;
    }
    __syncthreads();
#pragma unroll 16
    for (int nn = 0; nn < 64; ++nn) {
      const float2 kk = *(const float2*)&Ks[nn][c0];
      const float2 vv = *(const float2*)&Vs[nn][d0];
      a00 = fmaf(kk.x, vv.x, a00); a01 = fmaf(kk.x, vv.y, a01);
      a10 = fmaf(kk.y, vv.x, a10); a11 = fmaf(kk.y, vv.y, a11);
    }
    __syncthreads();
  }
  float* op = kvout + ((size_t)bh * 64 + c0) * 64 + d0;
  op[0] = a00; op[1] = a01;
  op[64] = a10; op[65] = a11;
}

// ---------------------------------------------------------------------------
// Row-register depthwise conv: each thread computes ONE output row (28 x)
// for one channel; input row kept in registers, reused across KS dx-taps.
// Per-output loads drop 49 -> 7 (KS=7). All array indices compile-time.
// ---------------------------------------------------------------------------
template <int KS>
__device__ inline void conv_row(const float* __restrict__ vp,
                                const float* __restrict__ wt, int wstride,
                                int chl, float bv, int y, int c,
                                float* __restrict__ op) {
  constexpr int P = KS / 2;
  float acc[28];
#pragma unroll
  for (int x = 0; x < 28; ++x) acc[x] = bv;
#pragma unroll
  for (int dy = 0; dy < KS; ++dy) {
    const int yy = y + dy - P;
    if (yy < 0 || yy >= 28) continue;  // wave-uniform (y uniform per wave)
    float rin[28 + 2 * P];
#pragma unroll
    for (int xx = 0; xx < 28 + 2 * P; ++xx) {
      const int gx = xx - P;
      rin[xx] = (gx >= 0 && gx < 28) ? vp[(size_t)(yy * 28 + gx) * CH + c] : 0.f;
    }
#pragma unroll
    for (int dx = 0; dx < KS; ++dx) {
      const float wv = wt[(dy * KS + dx) * wstride + chl];
#pragma unroll
      for (int x = 0; x < 28; ++x) acc[x] = fmaf(wv, rin[x + dx], acc[x]);
    }
  }
#pragma unroll
  for (int x = 0; x < 28; ++x) op[(size_t)(y * 28 + x) * CH + c] = acc[x];
}

__global__ __launch_bounds__(256) void dwconv_all(const float* __restrict__ v,
                                                  const float* __restrict__ wt3,
                                                  const float* __restrict__ cb3,
                                                  const float* __restrict__ wt5,
                                                  const float* __restrict__ cb5,
                                                  const float* __restrict__ wt7,
                                                  const float* __restrict__ cb7,
                                                  float* __restrict__ out) {
  const int bh = blockIdx.x;
  const int head = bh & 7;
  const int t = threadIdx.x;
  const int c = t & 63, slot = t >> 6;
  const int y = blockIdx.y * 4 + slot;  // 7 bands x 4 rows = 28
  const float* vp = v + ((size_t)bh * N_ + 1) * CH;
  float* op = out + (size_t)bh * HW_ * CH;
  if (head < 2) {
    const int chl = head * 64 + c;
    conv_row<3>(vp, wt3, 128, chl, cb3[chl], y, c, op);
  } else if (head < 5) {
    const int chl = (head - 2) * 64 + c;
    conv_row<5>(vp, wt5, 192, chl, cb5[chl], y, c, op);
  } else {
    const int chl = (head - 5) * 64 + c;
    conv_row<7>(vp, wt7, 192, chl, cb7[chl], y, c, op);
  }
}

// ---------------------------------------------------------------------------
// att (bf16) = 0.125*(q@kv) + (n>0 ? q[n][d]*conv_v[n-1][d] : 0)
// Epilogue: float4 conv_v loads + packed short4 bf16 stores (bit-identical).
// ---------------------------------------------------------------------------
__global__ __launch_bounds__(256) void att_kernel(const float* __restrict__ q,
                                                  const float* __restrict__ kv,
                                                  const float* __restrict__ conv_v,
                                                  __hip_bfloat16* __restrict__ att) {
  const int bh = blockIdx.x;
  const int b = bh >> 3, head = bh & 7;
  const int n0 = blockIdx.y * 64;
  const int t = threadIdx.x;
  __shared__ float Qs[64][68];
  __shared__ float KVs[64][68];
  const float* qp = q + (size_t)bh * N_ * CH;
  {
    const int lr = t >> 2;
    const int n = n0 + lr;
#pragma unroll
    for (int ch = 0; ch < 4; ++ch) {
      const int lk = ((t & 3) << 2) + ch * 16;
      float4 a4 = make_float4(0.f, 0.f, 0.f, 0.f);
      if (n < N_) a4 = *(const float4*)(qp + (size_t)n * CH + lk);
      Qs[lk + 0][lr] = a4.x; Qs[lk + 1][lr] = a4.y;
      Qs[lk + 2][lr] = a4.z; Qs[lk + 3][lr] = a4.w;
    }
    const float* kvp = kv + (size_t)bh * 64 * 64;
#pragma unroll
    for (int ch = 0; ch < 4; ++ch) {
      const int lin = ch * 1024 + t * 4;
      const int cc = lin >> 6, dd = lin & 63;
      const float4 b4 = *(const float4*)(kvp + lin);
      *(float4*)&KVs[cc][dd] = b4;
    }
  }
  __syncthreads();
  const int tx = t & 15, ty = t >> 4;
  float acc[4][4] = {};
#pragma unroll 16
  for (int kk = 0; kk < 64; ++kk) {
    const float4 a = *(const float4*)&Qs[kk][ty << 2];
    const float4 bb = *(const float4*)&KVs[kk][tx << 2];
    const float av[4] = {a.x, a.y, a.z, a.w};
    const float bv[4] = {bb.x, bb.y, bb.z, bb.w};
#pragma unroll
    for (int i = 0; i < 4; ++i)
#pragma unroll
      for (int j = 0; j < 4; ++j) acc[i][j] = fmaf(av[i], bv[j], acc[i][j]);
  }
  const float* cvp = conv_v + (size_t)bh * HW_ * CH;
  const int dd = tx << 2;
#pragma unroll
  for (int i = 0; i < 4; ++i) {
    const int nl = (ty << 2) + i, n = n0 + nl;
    if (n >= N_) break;
    float cv[4] = {0.f, 0.f, 0.f, 0.f};
    if (n > 0) {
      const float4 c4 = *(const float4*)(cvp + (size_t)(n - 1) * CH + dd);
      cv[0] = c4.x; cv[1] = c4.y; cv[2] = c4.z; cv[3] = c4.w;
    }
    union { __hip_bfloat16 h[4]; short4 s; } u;
#pragma unroll
    for (int j = 0; j < 4; ++j) {
      const float val = fmaf(Qs[dd + j][nl], cv[j], 0.125f * acc[i][j]);
      u.h[j] = __float2bfloat16(val);
    }
    *(short4*)&att[((size_t)b * N_ + n) * C_ + head * CH + dd] = u.s;
  }
}

extern "C" void kernel_launch(void* const* d_in, const int* in_sizes, int n_in,
                              void* d_out, int out_size, void* d_ws, size_t ws_size,
                              hipStream_t stream) {
  const float* x      = (const float*)d_in[0];
  const float* qkv_w  = (const float*)d_in[3];
  const float* proj_w = (const float*)d_in[4];
  const float* proj_b = (const float*)d_in[5];
  const float* cw3    = (const float*)d_in[6];
  const float* cb3    = (const float*)d_in[7];
  const float* cw5    = (const float*)d_in[8];
  const float* cb5    = (const float*)d_in[9];
  const float* cw7    = (const float*)d_in[10];
  const float* cb7    = (const float*)d_in[11];
  float* out = (float*)d_out;
  float* ws = (float*)d_ws;

  const size_t SZ = (size_t)B_ * NH * N_ * CH;  // 12,861,440 floats
  float* q  = ws;
  float* k  = ws + SZ;
  float* v  = ws + 2 * SZ;
  float* kv = ws + 3 * SZ;                       // 256*64*64 floats
  __hip_bfloat16* xb     = (__hip_bfloat16*)(ws + 3 * SZ + 256 * 64 * 64);
  __hip_bfloat16* qkvwb  = xb + SZ;              // 786432 bf16
  __hip_bfloat16* projwb = qkvwb + 786432;       // 262144 bf16
  float* wt3 = (float*)(projwb + 262144);        // 1152
  float* wt5 = wt3 + 1152;                       // 4800
  float* wt7 = wt5 + 4800;                       // 9408
  float* conv_v = k;                             // alias: k dead after kv_kernel
  __hip_bfloat16* attb = (__hip_bfloat16*)v;     // alias: v dead after dwconv

  cast_bf16<<<2048, 256, 0, stream>>>(x, xb, (int)(SZ / 8));
  cast_bf16<<<384, 256, 0, stream>>>(qkv_w, qkvwb, 786432 / 8);
  cast_bf16<<<128, 256, 0, stream>>>(proj_w, projwb, 262144 / 8);
  prep_weights<<<48, 256, 0, stream>>>(cw3, cw5, cw7, wt3, wt5, wt7);

  gemm_qkv_mfma<<<dim3(12, 197), 256, 0, stream>>>(xb, qkvwb, q, k, v);
  kv_kernel<<<dim3(256), 1024, 0, stream>>>(k, v, kv);
  dwconv_all<<<dim3(256, 7), 256, 0, stream>>>(v, wt3, cb3, wt5, cb5, wt7, cb7, conv_v);
  att_kernel<<<dim3(256, 13), 256, 0, stream>>>(q, kv, conv_v, attb);
  gemm_proj_mfma<<<dim3(4, 197), 256, 0, stream>>>(attb, projwb, proj_b, out);
}